// Round 1
// baseline (2383.834 us; speedup 1.0000x reference)
//
#include <hip/hip_runtime.h>
#include <math.h>

#define T_STEPS 100
#define BATCH   1024
#define INDIM   40
#define HID     512
#define NBLK    4
#define KPAD    576          // 64 (padded x) + 512 (h)
#define NG      2048         // 4*HID gate width

typedef int v4i __attribute__((ext_vector_type(4)));

// Bit-faithful emulation of the reference f32 _pact: sign(x)*0.5*((|x| - ||x|-a|) + a)
__device__ __forceinline__ float pact_f(float x, float a){
    float u = fabsf(x);
    float v = fabsf(u - a);
    float s = (x > 0.f) ? 1.f : ((x < 0.f) ? -1.f : 0.f);
    return (s * 0.5f) * ((u - v) + a);
}
// round(clip(x/a, -127/128, 127/128)*128), RNE — returns integer level
__device__ __forceinline__ int quant_int(float x, float inv_a){
    float xs = x * inv_a;
    xs = fminf(fmaxf(xs, -127.f/128.f), 127.f/128.f);
    return (int)rintf(xs * 128.f);
}
__device__ __forceinline__ int clamp127(int v){
    return v > 127 ? 127 : (v < -127 ? -127 : v);
}

// ---------------- setup kernels ----------------
__global__ __launch_bounds__(256) void k_quant_x(const float* __restrict__ x,
                                                 signed char* __restrict__ xq){
    int idx = blockIdx.x * 256 + threadIdx.x;     // over T*B*64
    int k = idx & 63; int tb = idx >> 6;
    signed char q = 0;
    if (k < INDIM){
        float xv = x[tb * INDIM + k];
        float pv = pact_f(xv, 128.f);
        q = (signed char)quant_int(pv, 1.f/128.f);
    }
    xq[idx] = q;
}

__global__ __launch_bounds__(256) void k_quant_w(const float* __restrict__ wih,
                                                 const float* __restrict__ whh,
                                                 signed char* __restrict__ wt){
    int idx = blockIdx.x * 256 + threadIdx.x;     // over NBLK*NG*KPAD
    int kk = idx % KPAD;
    int no = idx / KPAD;
    int o  = no % NG;
    int n  = no / NG;
    float w;
    if (kk < INDIM)      w = wih[((long)n*INDIM + kk)*NG + o];
    else if (kk < 64)    { wt[idx] = 0; return; }
    else                 w = whh[((long)n*HID + (kk-64))*NG + o];
    w = fminf(fmaxf(w, -1.f), 1.f);
    wt[idx] = (signed char)quant_int(w, 1.f);
}

__global__ __launch_bounds__(256) void k_quant_bias(const float* __restrict__ bih,
                                                    const float* __restrict__ bhh,
                                                    int* __restrict__ bihq,
                                                    int* __restrict__ bhhq){
    int idx = blockIdx.x * 256 + threadIdx.x;     // NBLK*NG
    bihq[idx] = quant_int(bih[idx], 1.f);
    bhhq[idx] = quant_int(bhh[idx], 1.f);
}

__global__ __launch_bounds__(256) void k_quant_fc(const float* __restrict__ fcw,
                                                  const float* __restrict__ fcb,
                                                  signed char* __restrict__ fcwt,
                                                  int* __restrict__ fcbq){
    int idx = blockIdx.x * 256 + threadIdx.x;     // NBLK*3*512
    if (idx < NBLK*3*512){
        int k = idx % 512; int nc = idx / 512; int c = nc % 3; int n = nc / 3;
        float w = fcw[((long)n*HID + k)*3 + c];
        w = fminf(fmaxf(w, -1.f), 1.f);
        fcwt[idx] = (signed char)quant_int(w, 1.f);
    }
    if (idx < NBLK*3) fcbq[idx] = quant_int(fcb[idx], 1.f);
}

__global__ void k_luts(signed char* __restrict__ sigl, signed char* __restrict__ thl){
    int i = threadIdx.x;
    if (i < 255){
        double xv = (double)(i - 127) / 32.0;
        float s = (float)(1.0 / (1.0 + exp(-xv)));
        float t = (float)tanh(xv);
        sigl[i] = (signed char)quant_int(pact_f(s, 1.f), 1.f);
        thl[i]  = (signed char)quant_int(pact_f(t, 1.f), 1.f);
    }
}

// ---------------- per-step gate GEMM ----------------
// G_int[n][m][o]: q12 from K=0..63 (x part, scale 1/128 -> *32 = /4),
//                 q13 from K=64..575 (h part, scale 1/4096 -> *32 = /128)
__global__ __launch_bounds__(256) void k_gates(const signed char* __restrict__ xq_t,
                                               const signed char* __restrict__ Hbuf,
                                               const signed char* __restrict__ Wt,
                                               const int* __restrict__ bihq,
                                               const int* __restrict__ bhhq,
                                               signed char* __restrict__ G){
    int bm = blockIdx.x, bn = blockIdx.y, n = blockIdx.z;
    __shared__ __align__(16) signed char As[128*64];   // [m][k]
    __shared__ __align__(16) signed char Bs[128*64];   // [o][k]
    int tid  = threadIdx.x;
    int lane = tid & 63;
    int wave = tid >> 6;
    int wm = wave >> 1, wn = wave & 1;

    v4i acc1[4][4] = {};   // x-part (kt==0)
    v4i acc2[4][4] = {};   // h-part (kt 1..8)

    int ar0 = tid >> 2;              // 0..63  (row within half-tile)
    int ac0 = (tid & 3) * 16;        // byte col
    const signed char* hrow0 = Hbuf + (long)n*BATCH*HID + (long)(bm*128 + ar0)*HID;
    const signed char* hrow1 = hrow0 + (long)64*HID;
    const signed char* wrow0 = Wt   + (long)n*NG*KPAD + (long)(bn*128 + ar0)*KPAD;
    const signed char* wrow1 = wrow0 + (long)64*KPAD;
    int4* as0 = (int4*)&As[tid*16]; int4* as1 = (int4*)&As[4096 + tid*16];
    int4* bs0 = (int4*)&Bs[tid*16]; int4* bs1 = (int4*)&Bs[4096 + tid*16];

    int ak = (lane >> 4) * 16;
    int am = wm*64 + (lane & 15);
    int bo = wn*64 + (lane & 15);

    for (int kt = 0; kt < 9; ++kt){
        int4 va0, va1, vb0, vb1;
        if (kt == 0){
            const int4* xs = (const int4*)(xq_t + (long)bm*8192);
            va0 = xs[tid]; va1 = xs[tid + 256];
        } else {
            int koff = (kt-1)*64 + ac0;
            va0 = *(const int4*)(hrow0 + koff);
            va1 = *(const int4*)(hrow1 + koff);
        }
        {
            int koff = kt*64 + ac0;
            vb0 = *(const int4*)(wrow0 + koff);
            vb1 = *(const int4*)(wrow1 + koff);
        }
        __syncthreads();
        *as0 = va0; *as1 = va1;
        *bs0 = vb0; *bs1 = vb1;
        __syncthreads();

        v4i af[4], bf[4];
        #pragma unroll
        for (int mi = 0; mi < 4; ++mi) af[mi] = *(const v4i*)&As[(am + mi*16)*64 + ak];
        #pragma unroll
        for (int ni = 0; ni < 4; ++ni) bf[ni] = *(const v4i*)&Bs[(bo + ni*16)*64 + ak];

        if (kt == 0){
            #pragma unroll
            for (int mi = 0; mi < 4; ++mi)
                #pragma unroll
                for (int ni = 0; ni < 4; ++ni)
                    acc1[mi][ni] = __builtin_amdgcn_mfma_i32_16x16x64_i8(af[mi], bf[ni], acc1[mi][ni], 0, 0, 0);
        } else {
            #pragma unroll
            for (int mi = 0; mi < 4; ++mi)
                #pragma unroll
                for (int ni = 0; ni < 4; ++ni)
                    acc2[mi][ni] = __builtin_amdgcn_mfma_i32_16x16x64_i8(af[mi], bf[ni], acc2[mi][ni], 0, 0, 0);
        }
    }

    long gb = (long)n * BATCH * NG;
    int col0 = bn*128 + wn*64 + (lane & 15);
    int row0 = bm*128 + wm*64 + ((lane >> 4) << 2);
    #pragma unroll
    for (int ni = 0; ni < 4; ++ni){
        int o  = col0 + ni*16;
        int b1 = bihq[n*NG + o];
        int b2 = 32 * bhhq[n*NG + o];
        #pragma unroll
        for (int mi = 0; mi < 4; ++mi){
            #pragma unroll
            for (int r = 0; r < 4; ++r){
                int S1  = acc1[mi][ni][r] + b1;
                int q12 = clamp127((int)rintf((float)S1 * 0.25f));
                int S2  = acc2[mi][ni][r] + b2;
                int q13 = clamp127((int)rintf((float)S2 * 0.0078125f));
                int g   = clamp127(q12 + q13);
                G[gb + (long)(row0 + mi*16 + r)*NG + o] = (signed char)g;
            }
        }
    }
}

// ---------------- per-step cell update ----------------
__global__ __launch_bounds__(256) void k_cell(const signed char* __restrict__ G,
                                              signed char* __restrict__ H,
                                              signed char* __restrict__ C,
                                              const signed char* __restrict__ sigl,
                                              const signed char* __restrict__ thl){
    __shared__ signed char s_sig[256], s_th[256];
    if (threadIdx.x < 255){ s_sig[threadIdx.x] = sigl[threadIdx.x]; s_th[threadIdx.x] = thl[threadIdx.x]; }
    __syncthreads();
    int idx = blockIdx.x * 256 + threadIdx.x;      // over NBLK*BATCH*HID/4
    long nb = idx >> 7;                            // n*1024+b
    int h4 = (idx & 127) << 2;
    const signed char* g = G + nb * NG;
    int iw = *(const int*)(g + h4);
    int jw = *(const int*)(g + 512  + h4);
    int fw = *(const int*)(g + 1024 + h4);
    int ow = *(const int*)(g + 1536 + h4);
    signed char* hp = H + nb*HID + h4;
    signed char* cp = C + nb*HID + h4;
    int cw = *(const int*)cp;
    int hout = 0, cout = 0;
    #pragma unroll
    for (int e = 0; e < 4; ++e){
        int sh = e * 8;
        int ii = (signed char)(iw >> sh);
        int jj = (signed char)(jw >> sh);
        int ff = (signed char)(fw >> sh);
        int oo = (signed char)(ow >> sh);
        int cc = (signed char)(cw >> sh);
        int fg = s_sig[ff + 127];
        int ig = s_sig[ii + 127];
        int jg = s_th [jj + 127];
        int og = s_sig[oo + 127];
        int gc = clamp127((int)rintf((float)(cc * fg) * 0.0078125f));   // /128
        int ai = clamp127((int)rintf((float)(ig * jg) * 0.0078125f));   // /128
        int nc = clamp127((int)rintf((float)(4*gc + ai) * 0.25f));      // /4
        int ac = s_th[nc + 127];
        int nh = clamp127((int)rintf((float)(ac * og) * (1.0f/512.0f)));// /512
        cout |= (nc & 255) << sh;
        hout |= (nh & 255) << sh;
    }
    *(int*)cp = cout;
    *(int*)hp = hout;
}

// ---------------- final fc ----------------
__global__ __launch_bounds__(256) void k_fc(const signed char* __restrict__ H,
                                            const signed char* __restrict__ fcwt,
                                            const int* __restrict__ fcbq,
                                            float* __restrict__ out){
    int wave = threadIdx.x >> 6, lane = threadIdx.x & 63;
    int nb = blockIdx.x * 4 + wave;                // n*1024+b
    int n = nb >> 10, b = nb & 1023;
    const signed char* h = H + (long)nb * HID + lane * 8;
    int2 hv = *(const int2*)h;
    int acc[3] = {0, 0, 0};
    #pragma unroll
    for (int c = 0; c < 3; ++c){
        const signed char* wp = fcwt + ((long)(n*3 + c))*512 + lane*8;
        int2 wv = *(const int2*)wp;
        int s = 0;
        #pragma unroll
        for (int e = 0; e < 4; ++e){
            s += (int)(signed char)(hv.x >> (8*e)) * (int)(signed char)(wv.x >> (8*e));
            s += (int)(signed char)(hv.y >> (8*e)) * (int)(signed char)(wv.y >> (8*e));
        }
        acc[c] = s;
    }
    #pragma unroll
    for (int off = 32; off; off >>= 1){
        acc[0] += __shfl_down(acc[0], off, 64);
        acc[1] += __shfl_down(acc[1], off, 64);
        acc[2] += __shfl_down(acc[2], off, 64);
    }
    if (lane == 0){
        #pragma unroll
        for (int c = 0; c < 3; ++c){
            int v = acc[c] + 32 * fcbq[n*3 + c];
            int q = clamp127((int)rintf((float)v * (1.0f/512.0f)));
            out[b*12 + n*3 + c] = (float)q * 0.125f;
        }
    }
}

extern "C" void kernel_launch(void* const* d_in, const int* in_sizes, int n_in,
                              void* d_out, int out_size, void* d_ws, size_t ws_size,
                              hipStream_t stream)
{
    const float* x   = (const float*)d_in[0];
    const float* wih = (const float*)d_in[1];
    const float* whh = (const float*)d_in[2];
    const float* bih = (const float*)d_in[3];
    const float* bhh = (const float*)d_in[4];
    const float* fcw = (const float*)d_in[6];
    const float* fcb = (const float*)d_in[7];
    float* out = (float*)d_out;
    (void)in_sizes; (void)n_in; (void)out_size; (void)ws_size;

    char* p = (char*)d_ws;
    auto alloc = [&](size_t nbytes){ char* r = p; p += (nbytes + 255) & ~(size_t)255; return r; };
    signed char* Xq   = (signed char*)alloc((size_t)T_STEPS*BATCH*64);
    signed char* Wt   = (signed char*)alloc((size_t)NBLK*NG*KPAD);
    signed char* G    = (signed char*)alloc((size_t)NBLK*BATCH*NG);
    signed char* Hb   = (signed char*)alloc((size_t)NBLK*BATCH*HID);
    signed char* Cb   = (signed char*)alloc((size_t)NBLK*BATCH*HID);
    int*         bihq = (int*)alloc((size_t)NBLK*NG*4);
    int*         bhhq = (int*)alloc((size_t)NBLK*NG*4);
    signed char* fcwt = (signed char*)alloc((size_t)NBLK*3*512);
    int*         fcbq = (int*)alloc((size_t)NBLK*3*4);
    signed char* sigl = (signed char*)alloc(256);
    signed char* thl  = (signed char*)alloc(256);

    k_quant_x   <<<(T_STEPS*BATCH*64)/256, 256, 0, stream>>>(x, Xq);
    k_quant_w   <<<(NBLK*NG*KPAD)/256,     256, 0, stream>>>(wih, whh, Wt);
    k_quant_bias<<<(NBLK*NG)/256,          256, 0, stream>>>(bih, bhh, bihq, bhhq);
    k_quant_fc  <<<(NBLK*3*512)/256,       256, 0, stream>>>(fcw, fcb, fcwt, fcbq);
    k_luts      <<<1, 256, 0, stream>>>(sigl, thl);
    hipMemsetAsync(Hb, 0, (size_t)2*NBLK*BATCH*HID, stream);   // Hb+Cb contiguous

    for (int t = 0; t < T_STEPS; ++t){
        k_gates<<<dim3(8,16,4), 256, 0, stream>>>(Xq + (size_t)t*BATCH*64, Hb, Wt, bihq, bhhq, G);
        k_cell <<<(NBLK*BATCH*HID/4)/256, 256, 0, stream>>>(G, Hb, Cb, sigl, thl);
    }
    k_fc<<<(NBLK*BATCH)/4, 256, 0, stream>>>(Hb, fcwt, fcbq, out);
}

// Round 2
// 1428.241 us; speedup vs baseline: 1.6691x; 1.6691x over previous
//
#include <hip/hip_runtime.h>
#include <math.h>

#define T_STEPS 100
#define BATCH   1024
#define INDIM   40
#define HID     512
#define NBLK    4
#define KPAD    576          // 64 (padded x) + 512 (h)
#define NG      2048         // 4*HID gate width
#define LDAP    80           // padded LDS row stride (bytes) for 64B k-slab

typedef int v4i __attribute__((ext_vector_type(4)));

// Bit-faithful emulation of the reference f32 _pact: sign(x)*0.5*((|x| - ||x|-a|) + a)
__device__ __forceinline__ float pact_f(float x, float a){
    float u = fabsf(x);
    float v = fabsf(u - a);
    float s = (x > 0.f) ? 1.f : ((x < 0.f) ? -1.f : 0.f);
    return (s * 0.5f) * ((u - v) + a);
}
// round(clip(x/a, -127/128, 127/128)*128), RNE — returns integer level
__device__ __forceinline__ int quant_int(float x, float inv_a){
    float xs = x * inv_a;
    xs = fminf(fmaxf(xs, -127.f/128.f), 127.f/128.f);
    return (int)rintf(xs * 128.f);
}
__device__ __forceinline__ int clamp127(int v){
    return v > 127 ? 127 : (v < -127 ? -127 : v);
}

// ---------------- setup kernels ----------------
__global__ __launch_bounds__(256) void k_quant_x(const float* __restrict__ x,
                                                 signed char* __restrict__ xq){
    int idx = blockIdx.x * 256 + threadIdx.x;     // over T*B*64
    int k = idx & 63; int tb = idx >> 6;
    signed char q = 0;
    if (k < INDIM){
        float xv = x[tb * INDIM + k];
        float pv = pact_f(xv, 128.f);
        q = (signed char)quant_int(pv, 1.f/128.f);
    }
    xq[idx] = q;
}

// W stored as Wt[n][c_new][k] with column permutation:
//   c_new = (h>>4)*64 + gate*16 + (h&15)   <->   o_orig = gate*512 + h
// so that an MFMA fragment group (4 x ni*16 cols) holds gates i,j,f,o of ONE h.
__global__ __launch_bounds__(256) void k_quant_w(const float* __restrict__ wih,
                                                 const float* __restrict__ whh,
                                                 signed char* __restrict__ wt){
    int idx = blockIdx.x * 256 + threadIdx.x;     // over NBLK*NG*KPAD
    int kk = idx % KPAD;
    int no = idx / KPAD;
    int c  = no % NG;
    int n  = no / NG;
    int gate = (c >> 4) & 3;
    int h    = ((c >> 6) << 4) | (c & 15);
    int o    = gate * 512 + h;
    float w;
    if (kk < INDIM)      w = wih[((long)n*INDIM + kk)*NG + o];
    else if (kk < 64)    { wt[idx] = 0; return; }
    else                 w = whh[((long)n*HID + (kk-64))*NG + o];
    w = fminf(fmaxf(w, -1.f), 1.f);
    wt[idx] = (signed char)quant_int(w, 1.f);
}

__global__ __launch_bounds__(256) void k_quant_bias(const float* __restrict__ bih,
                                                    const float* __restrict__ bhh,
                                                    int* __restrict__ bihq,
                                                    int* __restrict__ bhhq){
    int idx = blockIdx.x * 256 + threadIdx.x;     // NBLK*NG, permuted order
    int c = idx % NG; int n = idx / NG;
    int gate = (c >> 4) & 3;
    int h    = ((c >> 6) << 4) | (c & 15);
    int o    = gate * 512 + h;
    bihq[idx] = quant_int(bih[n*NG + o], 1.f);
    bhhq[idx] = quant_int(bhh[n*NG + o], 1.f);
}

__global__ __launch_bounds__(256) void k_quant_fc(const float* __restrict__ fcw,
                                                  const float* __restrict__ fcb,
                                                  signed char* __restrict__ fcwt,
                                                  int* __restrict__ fcbq){
    int idx = blockIdx.x * 256 + threadIdx.x;     // NBLK*3*512
    if (idx < NBLK*3*512){
        int k = idx % 512; int nc = idx / 512; int c = nc % 3; int n = nc / 3;
        float w = fcw[((long)n*HID + k)*3 + c];
        w = fminf(fmaxf(w, -1.f), 1.f);
        fcwt[idx] = (signed char)quant_int(w, 1.f);
    }
    if (idx < NBLK*3) fcbq[idx] = quant_int(fcb[idx], 1.f);
}

__global__ void k_luts(signed char* __restrict__ sigl, signed char* __restrict__ thl){
    int i = threadIdx.x;
    if (i < 255){
        double xv = (double)(i - 127) / 32.0;
        float s = (float)(1.0 / (1.0 + exp(-xv)));
        float t = (float)tanh(xv);
        sigl[i] = (signed char)quant_int(pact_f(s, 1.f), 1.f);
        thl[i]  = (signed char)quant_int(pact_f(t, 1.f), 1.f);
    }
}

// ---------------- fused per-step kernel: gates GEMM + cell update ----------------
// Grid: 512 blocks (XCD-swizzled), 256 threads (4 waves, 2m x 2n), 128x128 tile.
// Reads Hin[n][b][h], writes Hout[n][b][h] (ping-pong) and C[n][h][b] (exclusive).
__global__ __launch_bounds__(256, 2) void k_step(const signed char* __restrict__ xq_t,
                                                 const signed char* __restrict__ Hin,
                                                 signed char* __restrict__ Hout,
                                                 signed char* __restrict__ C,
                                                 const signed char* __restrict__ Wt,
                                                 const int* __restrict__ bihq,
                                                 const int* __restrict__ bhhq,
                                                 const signed char* __restrict__ sigl,
                                                 const signed char* __restrict__ thl){
    __shared__ __align__(16) signed char As[128*LDAP];
    __shared__ __align__(16) signed char Bs[128*LDAP];
    __shared__ signed char s_sig[256], s_th[256];

    // XCD swizzle: lid%8 = XCD; give each XCD all 8 bm for 8 (bn,n) panels
    int lid = blockIdx.x;
    int swz = (lid & 7) * 64 + (lid >> 3);
    int bm = swz & 7, bn = (swz >> 3) & 15, n = swz >> 7;

    int tid  = threadIdx.x;
    int lane = tid & 63;
    int wave = tid >> 6;
    int wm = wave >> 1, wn = wave & 1;

    if (tid < 255){ s_sig[tid] = sigl[tid]; s_th[tid] = thl[tid]; }

    // per-lane output coordinates
    int hglob = bn*32 + wn*16 + (lane & 15);                  // h unit this lane owns
    int rbase = bm*128 + wm*64 + ((lane >> 4) << 2);          // first of 4 rows per mi

    // bias preload (already column-permuted)
    int cbase = bn*128 + wn*64 + (lane & 15);
    int b1v[4], b2v[4];
    #pragma unroll
    for (int ni = 0; ni < 4; ++ni){
        int c = cbase + ni*16;
        b1v[ni] = bihq[n*NG + c];
        b2v[ni] = 32 * bhhq[n*NG + c];
    }
    // C preload: layout [n][h][b] -> word loads
    int* Cw = (int*)(C + ((long)(n*HID + hglob))*BATCH + rbase);
    int cold[4];
    #pragma unroll
    for (int mi = 0; mi < 4; ++mi) cold[mi] = Cw[mi*4];

    // staging pointers: thread stages rows (tid>>2) and (tid>>2)+64, 16B at col (tid&3)*16
    int sr = tid >> 2;
    int sc = (tid & 3) * 16;
    const signed char* wr0 = Wt  + (long)n*NG*KPAD   + (long)(bn*128 + sr)*KPAD + sc;
    const signed char* wr1 = wr0 + (long)64*KPAD;
    const signed char* hr0 = Hin + (long)n*BATCH*HID + (long)(bm*128 + sr)*HID  + sc;
    const signed char* hr1 = hr0 + (long)64*HID;
    int wlo = sr*LDAP + (tid & 3)*16;
    int whi = wlo + 64*LDAP;

    // prologue: tile kt=0 (x part) into regs
    int4 ra0 = *(const int4*)(xq_t + (long)bm*8192 + tid*16);
    int4 ra1 = *(const int4*)(xq_t + (long)bm*8192 + 4096 + tid*16);
    int4 rb0 = *(const int4*)(wr0);
    int4 rb1 = *(const int4*)(wr1);

    v4i acc1[4][4] = {};   // x-part (kt==0)
    v4i acc2[4][4] = {};   // h-part (kt 1..8)
    int am = wm*64 + (lane & 15);
    int bo = wn*64 + (lane & 15);
    int ak = (lane >> 4) * 16;

    for (int kt = 0; kt < 9; ++kt){
        __syncthreads();                       // prev LDS reads done; vmcnt drained for reg use
        *(int4*)&As[wlo] = ra0; *(int4*)&As[whi] = ra1;
        *(int4*)&Bs[wlo] = rb0; *(int4*)&Bs[whi] = rb1;
        __syncthreads();
        if (kt < 8){                           // issue next tile; latency hides under compute
            ra0 = *(const int4*)(hr0 + kt*64);
            ra1 = *(const int4*)(hr1 + kt*64);
            rb0 = *(const int4*)(wr0 + (kt+1)*64);
            rb1 = *(const int4*)(wr1 + (kt+1)*64);
        }
        v4i af[4], bf[4];
        #pragma unroll
        for (int mi = 0; mi < 4; ++mi) af[mi] = *(const v4i*)&As[(am + mi*16)*LDAP + ak];
        #pragma unroll
        for (int ni = 0; ni < 4; ++ni) bf[ni] = *(const v4i*)&Bs[(bo + ni*16)*LDAP + ak];
        if (kt == 0){
            #pragma unroll
            for (int mi = 0; mi < 4; ++mi)
                #pragma unroll
                for (int ni = 0; ni < 4; ++ni)
                    acc1[mi][ni] = __builtin_amdgcn_mfma_i32_16x16x64_i8(af[mi], bf[ni], acc1[mi][ni], 0, 0, 0);
        } else {
            #pragma unroll
            for (int mi = 0; mi < 4; ++mi)
                #pragma unroll
                for (int ni = 0; ni < 4; ++ni)
                    acc2[mi][ni] = __builtin_amdgcn_mfma_i32_16x16x64_i8(af[mi], bf[ni], acc2[mi][ni], 0, 0, 0);
        }
    }

    // fused epilogue: quantize gates + LSTM cell update, write Hout and C
    long hb = (long)n * BATCH;
    #pragma unroll
    for (int mi = 0; mi < 4; ++mi){
        int cw = cold[mi];
        int cnew = 0;
        #pragma unroll
        for (int r = 0; r < 4; ++r){
            int g4[4];
            #pragma unroll
            for (int ni = 0; ni < 4; ++ni){
                int S1  = acc1[mi][ni][r] + b1v[ni];
                int q12 = clamp127((int)rintf((float)S1 * 0.25f));
                int S2  = acc2[mi][ni][r] + b2v[ni];
                int q13 = clamp127((int)rintf((float)S2 * 0.0078125f));
                g4[ni]  = clamp127(q12 + q13);
            }
            int ig = s_sig[g4[0] + 127];
            int jg = s_th [g4[1] + 127];
            int fg = s_sig[g4[2] + 127];
            int og = s_sig[g4[3] + 127];
            int cc = (signed char)(cw >> (8*r));
            int gc = clamp127((int)rintf((float)(cc * fg) * 0.0078125f));   // /128
            int ai = clamp127((int)rintf((float)(ig * jg) * 0.0078125f));   // /128
            int nc = clamp127((int)rintf((float)(4*gc + ai) * 0.25f));      // /4
            int ac = s_th[nc + 127];
            int nh = clamp127((int)rintf((float)(ac * og) * (1.0f/512.0f)));// /512
            cnew |= (nc & 255) << (8*r);
            Hout[(hb + rbase + mi*16 + r)*HID + hglob] = (signed char)nh;
        }
        Cw[mi*4] = cnew;
    }
}

// ---------------- final fc ----------------
__global__ __launch_bounds__(256) void k_fc(const signed char* __restrict__ H,
                                            const signed char* __restrict__ fcwt,
                                            const int* __restrict__ fcbq,
                                            float* __restrict__ out){
    int wave = threadIdx.x >> 6, lane = threadIdx.x & 63;
    int nb = blockIdx.x * 4 + wave;                // n*1024+b
    int n = nb >> 10, b = nb & 1023;
    const signed char* h = H + (long)nb * HID + lane * 8;
    int2 hv = *(const int2*)h;
    int acc[3] = {0, 0, 0};
    #pragma unroll
    for (int c = 0; c < 3; ++c){
        const signed char* wp = fcwt + ((long)(n*3 + c))*512 + lane*8;
        int2 wv = *(const int2*)wp;
        int s = 0;
        #pragma unroll
        for (int e = 0; e < 4; ++e){
            s += (int)(signed char)(hv.x >> (8*e)) * (int)(signed char)(wv.x >> (8*e));
            s += (int)(signed char)(hv.y >> (8*e)) * (int)(signed char)(wv.y >> (8*e));
        }
        acc[c] = s;
    }
    #pragma unroll
    for (int off = 32; off; off >>= 1){
        acc[0] += __shfl_down(acc[0], off, 64);
        acc[1] += __shfl_down(acc[1], off, 64);
        acc[2] += __shfl_down(acc[2], off, 64);
    }
    if (lane == 0){
        #pragma unroll
        for (int c = 0; c < 3; ++c){
            int v = acc[c] + 32 * fcbq[n*3 + c];
            int q = clamp127((int)rintf((float)v * (1.0f/512.0f)));
            out[b*12 + n*3 + c] = (float)q * 0.125f;
        }
    }
}

extern "C" void kernel_launch(void* const* d_in, const int* in_sizes, int n_in,
                              void* d_out, int out_size, void* d_ws, size_t ws_size,
                              hipStream_t stream)
{
    const float* x   = (const float*)d_in[0];
    const float* wih = (const float*)d_in[1];
    const float* whh = (const float*)d_in[2];
    const float* bih = (const float*)d_in[3];
    const float* bhh = (const float*)d_in[4];
    const float* fcw = (const float*)d_in[6];
    const float* fcb = (const float*)d_in[7];
    float* out = (float*)d_out;
    (void)in_sizes; (void)n_in; (void)out_size; (void)ws_size;

    char* p = (char*)d_ws;
    auto alloc = [&](size_t nbytes){ char* r = p; p += (nbytes + 255) & ~(size_t)255; return r; };
    signed char* Xq   = (signed char*)alloc((size_t)T_STEPS*BATCH*64);
    signed char* Wt   = (signed char*)alloc((size_t)NBLK*NG*KPAD);
    signed char* Hb0  = (signed char*)alloc((size_t)NBLK*BATCH*HID);
    signed char* Hb1  = (signed char*)alloc((size_t)NBLK*BATCH*HID);
    signed char* Cb   = (signed char*)alloc((size_t)NBLK*BATCH*HID);
    int*         bihq = (int*)alloc((size_t)NBLK*NG*4);
    int*         bhhq = (int*)alloc((size_t)NBLK*NG*4);
    signed char* fcwt = (signed char*)alloc((size_t)NBLK*3*512);
    int*         fcbq = (int*)alloc((size_t)NBLK*3*4);
    signed char* sigl = (signed char*)alloc(256);
    signed char* thl  = (signed char*)alloc(256);

    k_quant_x   <<<(T_STEPS*BATCH*64)/256, 256, 0, stream>>>(x, Xq);
    k_quant_w   <<<(NBLK*NG*KPAD)/256,     256, 0, stream>>>(wih, whh, Wt);
    k_quant_bias<<<(NBLK*NG)/256,          256, 0, stream>>>(bih, bhh, bihq, bhhq);
    k_quant_fc  <<<(NBLK*3*512)/256,       256, 0, stream>>>(fcw, fcb, fcwt, fcbq);
    k_luts      <<<1, 256, 0, stream>>>(sigl, thl);
    hipMemsetAsync(Hb0, 0, (size_t)3*NBLK*BATCH*HID, stream);   // Hb0+Hb1+Cb contiguous

    for (int t = 0; t < T_STEPS; ++t){
        const signed char* Hi = (t & 1) ? Hb1 : Hb0;
        signed char*       Ho = (t & 1) ? Hb0 : Hb1;
        k_step<<<512, 256, 0, stream>>>(Xq + (size_t)t*BATCH*64, Hi, Ho, Cb, Wt, bihq, bhhq, sigl, thl);
    }
    k_fc<<<(NBLK*BATCH)/4, 256, 0, stream>>>(Hb0, fcwt, fcbq, out);   // t=99 wrote Hb0
}